// Round 18
// baseline (254.894 us; speedup 1.0000x reference)
//
#include <hip/hip_runtime.h>

#define N_NODES 100000
#define E_EDGES 1600000
#define DIM 128
#define HID 64
#define NGRAPH 8
#define EPSBN 1e-5f

// ---- radix partition (512-node groups) ----
#define GSHIFT 9
#define GNODES (1 << GSHIFT)                              // 512 nodes/group
#define NGROUP ((N_NODES + GNODES - 1) >> GSHIFT)         // 196 groups
#define GCAP 10240      // mean 8163, sigma ~90 -> 23-sigma margin
#define CHUNK 2048      // edges per partition block
#define PBLK 256
#define EPT (CHUNK / PBLK)                                // 8 edges/thread
#define NCHUNK ((E_EDGES + CHUNK - 1) / CHUNK)            // 782
#define MM1B ((N_NODES + 63) / 64)                        // 1563 mm1 blocks
#define GATB 2048                                         // gather blocks

#if __has_builtin(__builtin_amdgcn_cvt_pk_fp8_f32) && \
    __has_builtin(__builtin_amdgcn_cvt_pk_f32_fp8)
#define HW_FP8 1
#else
#define HW_FP8 0
#endif

typedef float floatx2 __attribute__((ext_vector_type(2)));
typedef short bf16x8 __attribute__((ext_vector_type(8)));
typedef float f32x4 __attribute__((ext_vector_type(4)));

// positional layout: position p (0..63) <-> column 16*(p&3) + (p>>2)
__device__ __forceinline__ int colOfPos(int p) {
  return 16 * (p & 3) + (p >> 2);
}

// f32 pair -> packed bf16x2 (RNE)
__device__ __forceinline__ unsigned f2bf_pack(float lo, float hi) {
  unsigned ul = __float_as_uint(lo);
  unsigned uh = __float_as_uint(hi);
  ul = (ul + 0x7fffu + ((ul >> 16) & 1u)) >> 16;
  uh = (uh + 0x7fffu + ((uh >> 16) & 1u)) >> 16;
  return (uh << 16) | ul;
}
__device__ __forceinline__ float bflo(unsigned u) {
  return __uint_as_float(u << 16);
}
__device__ __forceinline__ float bfhi(unsigned u) {
  return __uint_as_float(u & 0xffff0000u);
}

#if !HW_FP8
// software f32 -> fp8 e4m3 (OCP), RNE, clamp
__device__ __forceinline__ unsigned char f32_to_e4m3(float f) {
  unsigned u = __float_as_uint(f);
  unsigned s = (u >> 24) & 0x80u;
  float a = fabsf(f);
  if (a >= 464.f) return (unsigned char)(s | 0x7E);
  if (a < 0.015625f) {
    int m = (int)rintf(a * 512.f);
    if (m >= 8) return (unsigned char)(s | 0x08);
    return (unsigned char)(s | (unsigned)m);
  }
  int e = (int)((u >> 23) & 0xFF) - 127;
  float q = ldexpf(a, -e) * 8.f;
  int m = (int)rintf(q);
  if (m == 16) { m = 8; ++e; }
  if (e > 8) return (unsigned char)(s | 0x7E);
  return (unsigned char)(s | (unsigned)(((e + 7) << 3) | (m - 8)));
}
#endif

__device__ __forceinline__ unsigned pack4_e4m3(float a, float b, float c,
                                               float d) {
#if HW_FP8
  int w = __builtin_amdgcn_cvt_pk_fp8_f32(a, b, 0, false);
  w = __builtin_amdgcn_cvt_pk_fp8_f32(c, d, w, true);
  return (unsigned)w;
#else
  return (unsigned)f32_to_e4m3(a) | ((unsigned)f32_to_e4m3(b) << 8) |
         ((unsigned)f32_to_e4m3(c) << 16) | ((unsigned)f32_to_e4m3(d) << 24);
#endif
}

// ---------------------------------------------------------------------------
// wprep: one-time W transpose+bf16.  wTbf[n][kp] = bf16x2(W[2kp][n], W[2kp+1][n])
// n<64 -> W1l col n; n>=64 -> W1r col n-64.  128 blocks x 64 threads.
// ---------------------------------------------------------------------------
__global__ __launch_bounds__(64) void wprep_kernel(
    const float* __restrict__ W1l, const float* __restrict__ W1r,
    unsigned* __restrict__ wTbf) {
  int n = blockIdx.x;    // 0..127
  int kp = threadIdx.x;  // 0..63
  const float* Wc = (n < 64) ? (W1l + n) : (W1r + (n - 64));
  float w0 = Wc[(size_t)(2 * kp) * HID];
  float w1 = Wc[(size_t)(2 * kp + 1) * HID];
  wTbf[n * 64 + kp] = f2bf_pack(w0, w1);
}

// ---------------------------------------------------------------------------
// K1: blocks [0, NCHUNK) = partition;  blocks [NCHUNK, ..) = mm1 via MFMA.
// mm1: x tile -> bf16 LDS [64][136] (17.4 KB, the ONLY LDS); B-frags load
// straight from global wTbf (L2-hot).  Epilogue packs y1 fp8 / y2 bf16
// directly from accumulator fragments in POSITIONAL layout
// (position p = l15*4+j <-> col 16j+l15), consumed consistently downstream.
// ---------------------------------------------------------------------------
__global__ __launch_bounds__(PBLK) void part_mm1_kernel(
    const int* __restrict__ src, const int* __restrict__ dst,
    int* __restrict__ gcnt, unsigned* __restrict__ part,
    const float* __restrict__ x, const unsigned* __restrict__ wTbf,
    unsigned char* __restrict__ y1f8, unsigned* __restrict__ y2bf) {
  __shared__ __align__(16) unsigned char smraw[17536];

  if (blockIdx.x < NCHUNK) {
    // ---------------- partition ----------------
    int* hist = (int*)(smraw);
    int* sc = (int*)(smraw + 1024);
    int* scanoff = (int*)(smraw + 2048);
    int* gbase = (int*)(smraw + 3072);
    unsigned* buf = (unsigned*)(smraw + 4096);   // 8 KB
    unsigned char* gid = smraw + 12288;          // 2 KB

    int c = blockIdx.x;
    int e0 = c * CHUNK;
    int m = E_EDGES - e0;
    m = m < CHUNK ? m : CHUNK;
    int t = threadIdx.x;

    hist[t] = 0;
    __syncthreads();

    int myg[EPT];
    unsigned mytok[EPT];
    int myrank[EPT];
    #pragma unroll
    for (int q = 0; q < EPT; ++q) {
      int i = t + q * PBLK;
      if (i < m) {
        int d = dst[e0 + i];
        int s = src[e0 + i];
        int g = d >> GSHIFT;
        myg[q] = g;
        mytok[q] = ((unsigned)(d & (GNODES - 1)) << 17) | (unsigned)s;
        myrank[q] = atomicAdd(&hist[g], 1);
      } else {
        myg[q] = -1;
      }
    }
    __syncthreads();

    sc[t] = hist[t];
    if (t < NGROUP && hist[t] > 0) gbase[t] = atomicAdd(&gcnt[t], hist[t]);
    __syncthreads();
    for (int off = 1; off < 256; off <<= 1) {
      int add = (t >= off) ? sc[t - off] : 0;
      __syncthreads();
      sc[t] += add;
      __syncthreads();
    }
    scanoff[t] = sc[t] - hist[t];
    __syncthreads();

    #pragma unroll
    for (int q = 0; q < EPT; ++q) {
      if (myg[q] >= 0) {
        int pos = scanoff[myg[q]] + myrank[q];
        buf[pos] = mytok[q];
        gid[pos] = (unsigned char)myg[q];
      }
    }
    __syncthreads();

    for (int i = t; i < m; i += PBLK) {
      int g = gid[i];
      int addr = gbase[g] + (i - scanoff[g]);
      if (addr < GCAP) part[(size_t)g * GCAP + addr] = buf[i];
    }
  } else {
    // ---------------- mm1 (MFMA, lean LDS) ----------------
    short* xs = (short*)smraw;  // [64][136] bf16, 17408 B
    int t = threadIdx.x;
    int brow = (blockIdx.x - NCHUNK) * 64;

    // stage x -> bf16 LDS (coalesced reads, padded rows)
    for (int i = t; i < 64 * 32; i += PBLK) {
      int r = i >> 5;
      int c4 = (i & 31) << 2;
      int n = brow + r;
      unsigned lo = 0u, hi = 0u;
      if (n < N_NODES) {
        float4 v = *reinterpret_cast<const float4*>(x + (size_t)n * DIM + c4);
        lo = f2bf_pack(v.x, v.y);
        hi = f2bf_pack(v.z, v.w);
      }
      unsigned* dp = (unsigned*)(xs + r * 136 + c4);
      dp[0] = lo;
      dp[1] = hi;
    }
    __syncthreads();

    int lane = t & 63;
    int w = t >> 6;
    int l15 = lane & 15;
    int lg = lane >> 4;

    f32x4 acc[8];
    #pragma unroll
    for (int j = 0; j < 8; ++j) acc[j] = (f32x4){0.f, 0.f, 0.f, 0.f};

    #pragma unroll
    for (int ks = 0; ks < 4; ++ks) {
      int k0 = ks * 32 + lg * 8;
      bf16x8 a = *(const bf16x8*)(xs + (w * 16 + l15) * 136 + k0);
      // preload 8 B-frags for this ks from global (L2-hot)
      bf16x8 bfr[8];
      #pragma unroll
      for (int nf = 0; nf < 8; ++nf) {
        const uint4* bp = reinterpret_cast<const uint4*>(
            wTbf + (nf * 16 + l15) * 64 + ks * 16 + lg * 4);
        uint4 bv = *bp;
        bfr[nf] = *(const bf16x8*)&bv;
      }
      #pragma unroll
      for (int nf = 0; nf < 8; ++nf)
        acc[nf] =
            __builtin_amdgcn_mfma_f32_16x16x32_bf16(a, bfr[nf], acc[nf], 0,
                                                    0, 0);
    }

    // direct pack epilogue, positional layout (pos = l15*4+j <-> col 16j+l15)
    #pragma unroll
    for (int rg = 0; rg < 4; ++rg) {
      int r = w * 16 + lg * 4 + rg;
      int n = brow + r;
      if (n < N_NODES) {
        unsigned p1 = pack4_e4m3(acc[0][rg], acc[1][rg], acc[2][rg],
                                 acc[3][rg]);
        *reinterpret_cast<unsigned*>(y1f8 + (size_t)n * HID + l15 * 4) = p1;
        uint2 p2;
        p2.x = f2bf_pack(acc[4][rg], acc[5][rg]);
        p2.y = f2bf_pack(acc[6][rg], acc[7][rg]);
        *reinterpret_cast<uint2*>(y2bf + (size_t)n * (HID / 2) + l15 * 2) =
            p2;
      }
    }
  }
}

// ---------------------------------------------------------------------------
// groupcsr: one 512-thread block per 512-node group; LDS hist -> scan ->
// rowptr + csr scatter.  Emits tok2 = deg(10b)<<20 | batch(3b)<<17 | src(17b).
// ---------------------------------------------------------------------------
__global__ __launch_bounds__(512) void groupcsr_kernel(
    const int* __restrict__ gcnt, const unsigned* __restrict__ part,
    const int* __restrict__ batch, int* __restrict__ rowptr,
    int* __restrict__ csr, unsigned* __restrict__ tok2) {
  __shared__ int hist[GNODES];
  __shared__ int excl[GNODES];
  __shared__ int degl[GNODES];
  __shared__ int batl[GNODES];
  __shared__ int sc2[256];
  int g = blockIdx.x;
  int t = threadIdx.x;

  if (t < 256) sc2[t] = (t < NGROUP) ? min(gcnt[t], GCAP) : 0;
  __syncthreads();
  for (int off = 1; off < 256; off <<= 1) {
    int add = (t < 256 && t >= off) ? sc2[t - off] : 0;
    __syncthreads();
    if (t < 256) sc2[t] += add;
    __syncthreads();
  }
  int gbase = (g > 0) ? sc2[g - 1] : 0;

  hist[t] = 0;
  {
    int n = (g << GSHIFT) + t;
    batl[t] = (n < N_NODES) ? batch[n] : 0;
  }
  __syncthreads();

  int cnt = min(gcnt[g], GCAP);
  const unsigned* ga = part + (size_t)g * GCAP;
  for (int i = t; i < cnt; i += 512) atomicAdd(&hist[ga[i] >> 17], 1);
  __syncthreads();

  int orig = hist[t];
  degl[t] = orig;
  for (int off = 1; off < GNODES; off <<= 1) {
    int add = (t >= off) ? hist[t - off] : 0;
    __syncthreads();
    hist[t] += add;
    __syncthreads();
  }
  excl[t] = hist[t] - orig;
  __syncthreads();

  int n = (g << GSHIFT) + t;
  if (n <= N_NODES) rowptr[n] = gbase + excl[t];
  if (g == 0 && t == 0) rowptr[0] = 0;
  __syncthreads();

  for (int i = t; i < cnt; i += 512) {
    unsigned p = ga[i];
    int dloc = (int)(p >> 17);
    int pos = gbase + atomicAdd(&excl[dloc], 1);
    unsigned s = p & 0x1FFFFu;
    csr[pos] = (int)s;
    unsigned dg = (unsigned)degl[dloc];
    if (dg > 1023u) dg = 1023u;
    tok2[pos] = (dg << 20) | ((unsigned)batl[dloc] << 17) | s;
  }
}

// ---------------------------------------------------------------------------
// K3: blocks [0, NCHUNK) = partition2;  blocks [NCHUNK, ..) = gather
// (fp8 rows, node-per-oct).  Gather writes h_raw as PACKED BF16 (Cbf) in
// positional layout.  bias is indexed via the positional->column map.
// ---------------------------------------------------------------------------
__global__ __launch_bounds__(PBLK) void part2_gather_kernel(
    const unsigned* __restrict__ tok2, int* __restrict__ gcnt2,
    unsigned* __restrict__ part2, const uint2* __restrict__ yf8,
    const int* __restrict__ csr, const int* __restrict__ rowptr,
    const unsigned* __restrict__ otherbf, const float* __restrict__ bias,
    unsigned* __restrict__ outCbf, float* __restrict__ stats) {
  __shared__ int hist[256];
  __shared__ int sc[256];
  __shared__ int scanoff[256];
  __shared__ int gbase[256];
  __shared__ unsigned buf[CHUNK];
  __shared__ unsigned char gid[CHUNK];
  __shared__ float ss[HID];
  __shared__ float sq[HID];

  if (blockIdx.x < NCHUNK) {
    // ---------------- partition2 ----------------
    int c = blockIdx.x;
    int e0 = c * CHUNK;
    int m = E_EDGES - e0;
    m = m < CHUNK ? m : CHUNK;
    int t = threadIdx.x;

    hist[t] = 0;
    __syncthreads();

    int myg[EPT];
    unsigned mytok[EPT];
    int myrank[EPT];
    #pragma unroll
    for (int q = 0; q < EPT; ++q) {
      int i = t + q * PBLK;
      if (i < m) {
        unsigned p = tok2[e0 + i];
        int g = (int)((p & 0x1FFFFu) >> GSHIFT);
        myg[q] = g;
        mytok[q] = p;
        myrank[q] = atomicAdd(&hist[g], 1);
      } else {
        myg[q] = -1;
      }
    }
    __syncthreads();

    sc[t] = hist[t];
    if (t < NGROUP && hist[t] > 0) gbase[t] = atomicAdd(&gcnt2[t], hist[t]);
    __syncthreads();
    for (int off = 1; off < 256; off <<= 1) {
      int add = (t >= off) ? sc[t - off] : 0;
      __syncthreads();
      sc[t] += add;
      __syncthreads();
    }
    scanoff[t] = sc[t] - hist[t];
    __syncthreads();

    #pragma unroll
    for (int q = 0; q < EPT; ++q) {
      if (myg[q] >= 0) {
        int pos = scanoff[myg[q]] + myrank[q];
        buf[pos] = mytok[q];
        gid[pos] = (unsigned char)myg[q];
      }
    }
    __syncthreads();

    for (int i = t; i < m; i += PBLK) {
      int g = gid[i];
      int addr = gbase[g] + (i - scanoff[g]);
      if (addr < GCAP) part2[(size_t)g * GCAP + addr] = buf[i];
    }
  } else {
    // ---------------- gather (node per oct) ----------------
#if !HW_FP8
    __shared__ float tbl[256];
    {
      int t = threadIdx.x;
      if (t < 256) {
        int e = (t >> 3) & 15;
        int m = t & 7;
        float v = e ? ldexpf((float)(8 + m), e - 10) : ldexpf((float)m, -9);
        tbl[t] = (t & 0x80) ? -v : v;
      }
    }
    __syncthreads();
#endif
    int lane = threadIdx.x & 63;
    int oct = lane >> 3;
    int lo = lane & 7;
    int gbid = blockIdx.x - NCHUNK;
    int wid = (gbid * PBLK + (int)threadIdx.x) >> 6;
    const int nw = (GATB * PBLK) >> 6;

    float bj[8];
    #pragma unroll
    for (int k = 0; k < 8; ++k) bj[k] = bias[colOfPos(lo * 8 + k)];

    float ls[8], lq[8];
    #pragma unroll
    for (int k = 0; k < 8; ++k) { ls[k] = 0.f; lq[k] = 0.f; }

    for (int nb = wid * 8; nb < N_NODES; nb += nw * 8) {
      int n = nb + oct;
      bool valid = n < N_NODES;
      int start = valid ? rowptr[n] : 0;
      int end = valid ? rowptr[n + 1] : 0;

      float acc[8];
      #pragma unroll
      for (int k = 0; k < 8; ++k) acc[k] = 0.f;

      for (int bse = start; bse < end; bse += 8) {
        int m = end - bse;
        m = m < 8 ? m : 8;
        int e = bse + lo;
        int s = (e < end) ? csr[e] : 0;
        uint2 vv[8];
        #pragma unroll
        for (int i = 0; i < 8; ++i) {
          int si = __shfl(s, i, 8);          // broadcast within oct
          vv[i] = yf8[(size_t)si * 8 + lo];  // row-0 fallback for tail
        }
        #pragma unroll
        for (int i = 0; i < 8; ++i) {
          if (i < m) {
#if HW_FP8
            floatx2 p0 = __builtin_amdgcn_cvt_pk_f32_fp8((int)vv[i].x, false);
            floatx2 p1 = __builtin_amdgcn_cvt_pk_f32_fp8((int)vv[i].x, true);
            floatx2 p2 = __builtin_amdgcn_cvt_pk_f32_fp8((int)vv[i].y, false);
            floatx2 p3 = __builtin_amdgcn_cvt_pk_f32_fp8((int)vv[i].y, true);
            acc[0] += p0[0];
            acc[1] += p0[1];
            acc[2] += p1[0];
            acc[3] += p1[1];
            acc[4] += p2[0];
            acc[5] += p2[1];
            acc[6] += p3[0];
            acc[7] += p3[1];
#else
            acc[0] += tbl[vv[i].x & 255u];
            acc[1] += tbl[(vv[i].x >> 8) & 255u];
            acc[2] += tbl[(vv[i].x >> 16) & 255u];
            acc[3] += tbl[vv[i].x >> 24];
            acc[4] += tbl[vv[i].y & 255u];
            acc[5] += tbl[(vv[i].y >> 8) & 255u];
            acc[6] += tbl[(vv[i].y >> 16) & 255u];
            acc[7] += tbl[vv[i].y >> 24];
#endif
          }
        }
      }

      if (valid) {
        int deg = end - start;
        float inv = 1.f / (float)(deg > 1 ? deg : 1);
        uint4 ov = *reinterpret_cast<const uint4*>(otherbf +
                                                   (size_t)n * (HID / 2) +
                                                   lo * 4);
        float v[8];
        v[0] = fmaf(acc[0], inv, bj[0]) + bflo(ov.x);
        v[1] = fmaf(acc[1], inv, bj[1]) + bfhi(ov.x);
        v[2] = fmaf(acc[2], inv, bj[2]) + bflo(ov.y);
        v[3] = fmaf(acc[3], inv, bj[3]) + bfhi(ov.y);
        v[4] = fmaf(acc[4], inv, bj[4]) + bflo(ov.z);
        v[5] = fmaf(acc[5], inv, bj[5]) + bfhi(ov.z);
        v[6] = fmaf(acc[6], inv, bj[6]) + bflo(ov.w);
        v[7] = fmaf(acc[7], inv, bj[7]) + bfhi(ov.w);
        // h_raw packed bf16 (positional): 8 slots -> uint4
        uint4 cw4;
        cw4.x = f2bf_pack(v[0], v[1]);
        cw4.y = f2bf_pack(v[2], v[3]);
        cw4.z = f2bf_pack(v[4], v[5]);
        cw4.w = f2bf_pack(v[6], v[7]);
        *reinterpret_cast<uint4*>(outCbf + (size_t)n * (HID / 2) + lo * 4) =
            cw4;
        #pragma unroll
        for (int k = 0; k < 8; ++k) {
          ls[k] += v[k];
          lq[k] = fmaf(v[k], v[k], lq[k]);
        }
      }
    }

    int t = threadIdx.x;
    if (t < HID) { ss[t] = 0.f; sq[t] = 0.f; }
    __syncthreads();
    #pragma unroll
    for (int k = 0; k < 8; ++k) {
      atomicAdd(&ss[lo * 8 + k], ls[k]);   // positional
      atomicAdd(&sq[lo * 8 + k], lq[k]);
    }
    __syncthreads();
    if (t < HID) {
      unsafeAtomicAdd(&stats[t], ss[t]);
      unsafeAtomicAdd(&stats[HID + t], sq[t]);
    }
  }
}

// ---------------------------------------------------------------------------
// K4: chsum — fused caccum + hsum.  Positional lane layout; gamma/beta via
// colOfPos.  One 256-thread block per src-group.
// ---------------------------------------------------------------------------
__global__ __launch_bounds__(256) void chsum_kernel(
    const int* __restrict__ gcnt2, const unsigned* __restrict__ part2,
    const unsigned* __restrict__ Cbf, const float* __restrict__ stats,
    const float* __restrict__ gamma, const float* __restrict__ beta,
    const int* __restrict__ batch, float* __restrict__ S1g,
    float* __restrict__ S2g) {
  __shared__ float c[GNODES * NGRAPH];   // 16 KB
  __shared__ float r1[HID * NGRAPH];     // 2 KB
  __shared__ float r2[HID * NGRAPH];     // 2 KB
  int g = blockIdx.x;
  int t = threadIdx.x;

  for (int i = t; i < GNODES * NGRAPH; i += 256) c[i] = 0.f;
  for (int i = t; i < HID * NGRAPH; i += 256) { r1[i] = 0.f; r2[i] = 0.f; }
  __syncthreads();

  int cnt = min(gcnt2[g], GCAP);
  const unsigned* ga = part2 + (size_t)g * GCAP;
  for (int i = t; i < cnt; i += 256) {
    unsigned p = ga[i];
    int sl = (int)(p & (GNODES - 1));
    int b = (int)((p >> 17) & 7u);
    int deg = (int)((p >> 20) & 0x3FFu);
    float w = 1.f / (float)(deg > 1 ? deg : 1);
    atomicAdd(&c[sl * NGRAPH + b], w);
  }
  __syncthreads();

  int lane = t & 63;
  int wv = t >> 6;  // 4 waves
  int cl = colOfPos(lane);

  float inv_n = 1.0f / (float)N_NODES;
  float mu = stats[lane] * inv_n;     // positional
  float var = stats[HID + lane] * inv_n - mu * mu;
  float scl = gamma[cl] * rsqrtf(var + EPSBN);
  float shf = beta[cl] - mu * scl;

  float s1[NGRAPH], s2[NGRAPH];
  #pragma unroll
  for (int b = 0; b < NGRAPH; ++b) { s1[b] = 0.f; s2[b] = 0.f; }

  int nend = N_NODES - (g << GSHIFT);
  nend = nend < GNODES ? nend : GNODES;
  for (int nl = wv; nl < nend; nl += 4) {
    int n = (g << GSHIFT) + nl;
    unsigned u = Cbf[(size_t)n * (HID / 2) + (lane >> 1)];
    float hr = (lane & 1) ? bfhi(u) : bflo(u);
    float h = fmaf(hr, scl, shf);
    h = h > 0.f ? h : 0.f;
    int bn = batch[n];  // wave-uniform -> s_load
    #pragma unroll
    for (int b = 0; b < NGRAPH; ++b) {
      float cb = c[nl * NGRAPH + b];  // wave-uniform LDS broadcast
      s1[b] = fmaf(cb, h, s1[b]);
      s2[b] += (b == bn) ? h : 0.f;
    }
  }

  #pragma unroll
  for (int b = 0; b < NGRAPH; ++b) {
    atomicAdd(&r1[b * HID + lane], s1[b]);   // positional
    atomicAdd(&r2[b * HID + lane], s2[b]);
  }
  __syncthreads();
  for (int i = t; i < HID * NGRAPH; i += 256) {
    unsafeAtomicAdd(&S1g[i], r1[i]);
    unsafeAtomicAdd(&S2g[i], r2[i]);
  }
}

// ---------------------------------------------------------------------------
// finale: out[b,oc] = (S1[b]@W2l + S2[b]@W2r)[oc]/V_b + b2[oc]  (V_b>0)
// S1g/S2g are positional: position l holds column colOfPos(l).
// ---------------------------------------------------------------------------
__device__ __forceinline__ int lbound(const int* __restrict__ a, int key) {
  int lo = 0, hi = N_NODES;
  while (lo < hi) {
    int mid = (lo + hi) >> 1;
    if (a[mid] < key) lo = mid + 1; else hi = mid;
  }
  return lo;
}

__global__ __launch_bounds__(512) void finale_kernel(
    const float* __restrict__ S1g, const float* __restrict__ S2g,
    const int* __restrict__ batch, const float* __restrict__ W2l,
    const float* __restrict__ W2r, const float* __restrict__ b2,
    float* __restrict__ out) {
  int t = threadIdx.x;  // 512 = 8 graphs x 64 cols
  int b = t >> 6;
  int oc = t & 63;
  int V = lbound(batch, b + 1) - lbound(batch, b);
  float acc = 0.f;
  for (int l = 0; l < HID; ++l) {
    int k = colOfPos(l);
    acc = fmaf(S1g[b * HID + l], W2l[k * HID + oc], acc);
    acc = fmaf(S2g[b * HID + l], W2r[k * HID + oc], acc);
  }
  out[t] = (V > 0) ? (acc / (float)V + b2[oc]) : 0.f;
}

// ---------------------------------------------------------------------------
extern "C" void kernel_launch(void* const* d_in, const int* in_sizes, int n_in,
                              void* d_out, int out_size, void* d_ws,
                              size_t ws_size, hipStream_t stream) {
  const float* x      = (const float*)d_in[0];
  const int*   ei     = (const int*)d_in[1];
  const int*   batch  = (const int*)d_in[2];
  const float* W1l    = (const float*)d_in[3];
  const float* b1     = (const float*)d_in[4];
  const float* W1r    = (const float*)d_in[5];
  const float* gamma1 = (const float*)d_in[6];
  const float* beta1  = (const float*)d_in[7];
  const float* W2l    = (const float*)d_in[8];
  const float* b2     = (const float*)d_in[9];
  const float* W2r    = (const float*)d_in[10];

  const int* src = ei;            // edge_index[0]
  const int* dst = ei + E_EDGES;  // edge_index[1]

  float* ws = (float*)d_ws;
  size_t off = 0;
  unsigned char* Af8 = (unsigned char*)(ws + off);
  off += (size_t)N_NODES * HID / 4;                       // fp8 y1 (6.4 MB)
  unsigned* Bbf = (unsigned*)(ws + off);
  off += (size_t)N_NODES * (HID / 2);                     // bf16 y2 (12.8 MB)
  unsigned* Cbf = (unsigned*)(ws + off);
  off += (size_t)N_NODES * (HID / 2);                     // bf16 h_raw
  // zero-region start
  int* gcnt     = (int*)(ws + off); off += 256;
  int* gcnt2    = (int*)(ws + off); off += 256;
  float* stats  = ws + off; off += 2 * HID;
  float* S1g    = ws + off; off += NGRAPH * HID;
  float* S2g    = ws + off; off += NGRAPH * HID;
  size_t zero_elems = 256 + 256 + 2 * HID + 2 * NGRAPH * HID;
  // zero-region end
  unsigned* wTbf = (unsigned*)(ws + off); off += 128 * 64;
  int* rowptr   = (int*)(ws + off); off += N_NODES + 1;
  int* csr      = (int*)(ws + off); off += E_EDGES;
  unsigned* tok2 = (unsigned*)(ws + off); off += E_EDGES;
  unsigned* part = (unsigned*)(ws + off); off += (size_t)NGROUP * GCAP;
  // part is reused as part2 after groupcsr consumes it

  hipMemsetAsync(gcnt, 0, zero_elems * sizeof(float), stream);

  // K0: one-time W transpose + bf16 pack
  wprep_kernel<<<128, 64, 0, stream>>>(W1l, W1r, wTbf);

  // K1: partition || mm1-MFMA (independent; lean 17.4 KB LDS)
  part_mm1_kernel<<<NCHUNK + MM1B, PBLK, 0, stream>>>(
      src, dst, gcnt, part, x, wTbf, Af8, Bbf);

  // K2: groupcsr (needs partition)
  groupcsr_kernel<<<NGROUP, 512, 0, stream>>>(gcnt, part, batch, rowptr, csr,
                                              tok2);

  // K3: partition2 || gather (both need only K1+K2 outputs)
  part2_gather_kernel<<<NCHUNK + GATB, PBLK, 0, stream>>>(
      tok2, gcnt2, part, (const uint2*)Af8, csr, rowptr, Bbf, b1, Cbf, stats);

  // K4: chsum (fused caccum + hsum; needs part2 + gather outputs)
  chsum_kernel<<<NGROUP, 256, 0, stream>>>(gcnt2, part, Cbf, stats, gamma1,
                                           beta1, batch, S1g, S2g);

  // K5: finale
  finale_kernel<<<1, 512, 0, stream>>>(S1g, S2g, batch, W2l, W2r, b2,
                                       (float*)d_out);
}

// Round 19
// 223.641 us; speedup vs baseline: 1.1397x; 1.1397x over previous
//
#include <hip/hip_runtime.h>

#define N_NODES 100000
#define E_EDGES 1600000
#define DIM 128
#define HID 64
#define NGRAPH 8
#define EPSBN 1e-5f

// ---- radix partition (512-node groups) ----
#define GSHIFT 9
#define GNODES (1 << GSHIFT)                              // 512 nodes/group
#define NGROUP ((N_NODES + GNODES - 1) >> GSHIFT)         // 196 groups
#define GCAP 10240      // mean 8163, sigma ~90 -> 23-sigma margin
#define CHUNK 2048      // edges per partition block
#define PBLK 256
#define EPT (CHUNK / PBLK)                                // 8 edges/thread
#define NCHUNK ((E_EDGES + CHUNK - 1) / CHUNK)            // 782
#define MM1B ((N_NODES + 63) / 64)                        // 1563 mm1 blocks
#define GATB 2048                                         // gather blocks
#define WPREPB 32                                         // wprep blocks

#if __has_builtin(__builtin_amdgcn_cvt_pk_fp8_f32) && \
    __has_builtin(__builtin_amdgcn_cvt_pk_f32_fp8)
#define HW_FP8 1
#else
#define HW_FP8 0
#endif

typedef float floatx2 __attribute__((ext_vector_type(2)));
typedef short bf16x8 __attribute__((ext_vector_type(8)));
typedef float f32x4 __attribute__((ext_vector_type(4)));

// positional layout: position p (0..63) <-> column 16*(p&3) + (p>>2)
__device__ __forceinline__ int colOfPos(int p) {
  return 16 * (p & 3) + (p >> 2);
}

// f32 pair -> packed bf16x2 (RNE)
__device__ __forceinline__ unsigned f2bf_pack(float lo, float hi) {
  unsigned ul = __float_as_uint(lo);
  unsigned uh = __float_as_uint(hi);
  ul = (ul + 0x7fffu + ((ul >> 16) & 1u)) >> 16;
  uh = (uh + 0x7fffu + ((uh >> 16) & 1u)) >> 16;
  return (uh << 16) | ul;
}
__device__ __forceinline__ float bflo(unsigned u) {
  return __uint_as_float(u << 16);
}
__device__ __forceinline__ float bfhi(unsigned u) {
  return __uint_as_float(u & 0xffff0000u);
}

#if !HW_FP8
// software f32 -> fp8 e4m3 (OCP), RNE, clamp
__device__ __forceinline__ unsigned char f32_to_e4m3(float f) {
  unsigned u = __float_as_uint(f);
  unsigned s = (u >> 24) & 0x80u;
  float a = fabsf(f);
  if (a >= 464.f) return (unsigned char)(s | 0x7E);
  if (a < 0.015625f) {
    int m = (int)rintf(a * 512.f);
    if (m >= 8) return (unsigned char)(s | 0x08);
    return (unsigned char)(s | (unsigned)m);
  }
  int e = (int)((u >> 23) & 0xFF) - 127;
  float q = ldexpf(a, -e) * 8.f;
  int m = (int)rintf(q);
  if (m == 16) { m = 8; ++e; }
  if (e > 8) return (unsigned char)(s | 0x7E);
  return (unsigned char)(s | (unsigned)(((e + 7) << 3) | (m - 8)));
}
#endif

__device__ __forceinline__ unsigned pack4_e4m3(float a, float b, float c,
                                               float d) {
#if HW_FP8
  int w = __builtin_amdgcn_cvt_pk_fp8_f32(a, b, 0, false);
  w = __builtin_amdgcn_cvt_pk_fp8_f32(c, d, w, true);
  return (unsigned)w;
#else
  return (unsigned)f32_to_e4m3(a) | ((unsigned)f32_to_e4m3(b) << 8) |
         ((unsigned)f32_to_e4m3(c) << 16) | ((unsigned)f32_to_e4m3(d) << 24);
#endif
}

// ---------------------------------------------------------------------------
// KA: blocks [0, NCHUNK) = partition (lean 14.3 KB LDS, high occupancy);
//     blocks [NCHUNK, NCHUNK+WPREPB) = wprep (W transpose + bf16 pack).
// ---------------------------------------------------------------------------
__global__ __launch_bounds__(PBLK) void part_wprep_kernel(
    const int* __restrict__ src, const int* __restrict__ dst,
    int* __restrict__ gcnt, unsigned* __restrict__ part,
    const float* __restrict__ W1l, const float* __restrict__ W1r,
    unsigned* __restrict__ wTbf) {
  __shared__ int hist[256];
  __shared__ int sc[256];
  __shared__ int scanoff[256];
  __shared__ int gbase[256];
  __shared__ unsigned buf[CHUNK];
  __shared__ unsigned char gid[CHUNK];

  if (blockIdx.x < NCHUNK) {
    // ---------------- partition ----------------
    int c = blockIdx.x;
    int e0 = c * CHUNK;
    int m = E_EDGES - e0;
    m = m < CHUNK ? m : CHUNK;
    int t = threadIdx.x;

    hist[t] = 0;
    __syncthreads();

    int myg[EPT];
    unsigned mytok[EPT];
    int myrank[EPT];
    #pragma unroll
    for (int q = 0; q < EPT; ++q) {
      int i = t + q * PBLK;
      if (i < m) {
        int d = dst[e0 + i];
        int s = src[e0 + i];
        int g = d >> GSHIFT;
        myg[q] = g;
        mytok[q] = ((unsigned)(d & (GNODES - 1)) << 17) | (unsigned)s;
        myrank[q] = atomicAdd(&hist[g], 1);
      } else {
        myg[q] = -1;
      }
    }
    __syncthreads();

    sc[t] = hist[t];
    if (t < NGROUP && hist[t] > 0) gbase[t] = atomicAdd(&gcnt[t], hist[t]);
    __syncthreads();
    for (int off = 1; off < 256; off <<= 1) {
      int add = (t >= off) ? sc[t - off] : 0;
      __syncthreads();
      sc[t] += add;
      __syncthreads();
    }
    scanoff[t] = sc[t] - hist[t];
    __syncthreads();

    #pragma unroll
    for (int q = 0; q < EPT; ++q) {
      if (myg[q] >= 0) {
        int pos = scanoff[myg[q]] + myrank[q];
        buf[pos] = mytok[q];
        gid[pos] = (unsigned char)myg[q];
      }
    }
    __syncthreads();

    for (int i = t; i < m; i += PBLK) {
      int g = gid[i];
      int addr = gbase[g] + (i - scanoff[g]);
      if (addr < GCAP) part[(size_t)g * GCAP + addr] = buf[i];
    }
  } else {
    // ---------------- wprep ----------------
    int i = (blockIdx.x - NCHUNK) * PBLK + threadIdx.x;
    if (i < 128 * 64) {
      int n = i >> 6;
      int kp = i & 63;
      const float* Wc = (n < 64) ? (W1l + n) : (W1r + (n - 64));
      float w0 = Wc[(size_t)(2 * kp) * HID];
      float w1 = Wc[(size_t)(2 * kp + 1) * HID];
      wTbf[n * 64 + kp] = f2bf_pack(w0, w1);
    }
  }
}

// ---------------------------------------------------------------------------
// KB: blocks [0, MM1B) = mm1-MFMA (threads<256 compute; xs+wts LDS-staged;
//     direct positional epilogue);  blocks [MM1B, MM1B+NGROUP) = groupcsr.
// Independent work (mm1 needs only x/wTbf; groupcsr needs partition) fused
// to overlap on the CU array.
// ---------------------------------------------------------------------------
__global__ __launch_bounds__(512) void mm1_gcsr_kernel(
    const float* __restrict__ x, const unsigned* __restrict__ wTbf,
    unsigned char* __restrict__ y1f8, unsigned* __restrict__ y2bf,
    const int* __restrict__ gcnt, const unsigned* __restrict__ part,
    const int* __restrict__ batch, int* __restrict__ rowptr,
    int* __restrict__ csr, unsigned* __restrict__ tok2) {
  __shared__ __align__(16) unsigned char smraw[52224];

  if (blockIdx.x < MM1B) {
    // ---------------- mm1 (MFMA) ----------------
    short* xs = (short*)smraw;             // [64][136] bf16, 17408 B
    short* wts = (short*)(smraw + 17408);  // [128][136] bf16, 34816 B
    int t = threadIdx.x;
    int brow = blockIdx.x * 64;

    // stage x -> bf16 LDS (coalesced, all 512 threads)
    for (int i = t; i < 64 * 32; i += 512) {
      int r = i >> 5;
      int c4 = (i & 31) << 2;
      int n = brow + r;
      unsigned lo = 0u, hi = 0u;
      if (n < N_NODES) {
        float4 v = *reinterpret_cast<const float4*>(x + (size_t)n * DIM + c4);
        lo = f2bf_pack(v.x, v.y);
        hi = f2bf_pack(v.z, v.w);
      }
      unsigned* dp = (unsigned*)(xs + r * 136 + c4);
      dp[0] = lo;
      dp[1] = hi;
    }
    // stage wT
    for (int i = t; i < 128 * 64; i += 512) {
      int nn = i >> 6;
      int kp = i & 63;
      *(unsigned*)(wts + nn * 136 + kp * 2) = wTbf[i];
    }
    __syncthreads();

    if (t < 256) {
      int lane = t & 63;
      int w = t >> 6;
      int l15 = lane & 15;
      int lg = lane >> 4;

      f32x4 acc[8];
      #pragma unroll
      for (int j = 0; j < 8; ++j) acc[j] = (f32x4){0.f, 0.f, 0.f, 0.f};

      #pragma unroll
      for (int ks = 0; ks < 4; ++ks) {
        int k0 = ks * 32 + lg * 8;
        bf16x8 a = *(const bf16x8*)(xs + (w * 16 + l15) * 136 + k0);
        #pragma unroll
        for (int nf = 0; nf < 8; ++nf) {
          bf16x8 b = *(const bf16x8*)(wts + (nf * 16 + l15) * 136 + k0);
          acc[nf] =
              __builtin_amdgcn_mfma_f32_16x16x32_bf16(a, b, acc[nf], 0, 0, 0);
        }
      }

      // direct pack epilogue, positional (pos = l15*4+j <-> col 16j+l15)
      #pragma unroll
      for (int rg = 0; rg < 4; ++rg) {
        int r = w * 16 + lg * 4 + rg;
        int n = brow + r;
        if (n < N_NODES) {
          unsigned p1 = pack4_e4m3(acc[0][rg], acc[1][rg], acc[2][rg],
                                   acc[3][rg]);
          *reinterpret_cast<unsigned*>(y1f8 + (size_t)n * HID + l15 * 4) = p1;
          uint2 p2;
          p2.x = f2bf_pack(acc[4][rg], acc[5][rg]);
          p2.y = f2bf_pack(acc[6][rg], acc[7][rg]);
          *reinterpret_cast<uint2*>(y2bf + (size_t)n * (HID / 2) + l15 * 2) =
              p2;
        }
      }
    }
  } else {
    // ---------------- groupcsr ----------------
    int* hist = (int*)smraw;              // 2048 B
    int* excl = (int*)(smraw + 2048);     // 2048 B
    int* degl = (int*)(smraw + 4096);     // 2048 B
    int* batl = (int*)(smraw + 6144);     // 2048 B
    int* sc2 = (int*)(smraw + 8192);      // 1024 B
    int g = blockIdx.x - MM1B;
    int t = threadIdx.x;

    if (t < 256) sc2[t] = (t < NGROUP) ? min(gcnt[t], GCAP) : 0;
    __syncthreads();
    for (int off = 1; off < 256; off <<= 1) {
      int add = (t < 256 && t >= off) ? sc2[t - off] : 0;
      __syncthreads();
      if (t < 256) sc2[t] += add;
      __syncthreads();
    }
    int gbase = (g > 0) ? sc2[g - 1] : 0;

    hist[t] = 0;
    {
      int n = (g << GSHIFT) + t;
      batl[t] = (n < N_NODES) ? batch[n] : 0;
    }
    __syncthreads();

    int cnt = min(gcnt[g], GCAP);
    const unsigned* ga = part + (size_t)g * GCAP;
    for (int i = t; i < cnt; i += 512) atomicAdd(&hist[ga[i] >> 17], 1);
    __syncthreads();

    int orig = hist[t];
    degl[t] = orig;
    for (int off = 1; off < GNODES; off <<= 1) {
      int add = (t >= off) ? hist[t - off] : 0;
      __syncthreads();
      hist[t] += add;
      __syncthreads();
    }
    excl[t] = hist[t] - orig;
    __syncthreads();

    int n = (g << GSHIFT) + t;
    if (n <= N_NODES) rowptr[n] = gbase + excl[t];
    if (g == 0 && t == 0) rowptr[0] = 0;
    __syncthreads();

    for (int i = t; i < cnt; i += 512) {
      unsigned p = ga[i];
      int dloc = (int)(p >> 17);
      int pos = gbase + atomicAdd(&excl[dloc], 1);
      unsigned s = p & 0x1FFFFu;
      csr[pos] = (int)s;
      unsigned dg = (unsigned)degl[dloc];
      if (dg > 1023u) dg = 1023u;
      tok2[pos] = (dg << 20) | ((unsigned)batl[dloc] << 17) | s;
    }
  }
}

// ---------------------------------------------------------------------------
// KC: blocks [0, NCHUNK) = partition2;  blocks [NCHUNK, ..) = gather
// (fp8 rows, node-per-oct).  Positional layout throughout.
// ---------------------------------------------------------------------------
__global__ __launch_bounds__(PBLK) void part2_gather_kernel(
    const unsigned* __restrict__ tok2, int* __restrict__ gcnt2,
    unsigned* __restrict__ part2, const uint2* __restrict__ yf8,
    const int* __restrict__ csr, const int* __restrict__ rowptr,
    const unsigned* __restrict__ otherbf, const float* __restrict__ bias,
    unsigned* __restrict__ outCbf, float* __restrict__ stats) {
  __shared__ int hist[256];
  __shared__ int sc[256];
  __shared__ int scanoff[256];
  __shared__ int gbase[256];
  __shared__ unsigned buf[CHUNK];
  __shared__ unsigned char gid[CHUNK];
  __shared__ float ss[HID];
  __shared__ float sq[HID];

  if (blockIdx.x < NCHUNK) {
    // ---------------- partition2 ----------------
    int c = blockIdx.x;
    int e0 = c * CHUNK;
    int m = E_EDGES - e0;
    m = m < CHUNK ? m : CHUNK;
    int t = threadIdx.x;

    hist[t] = 0;
    __syncthreads();

    int myg[EPT];
    unsigned mytok[EPT];
    int myrank[EPT];
    #pragma unroll
    for (int q = 0; q < EPT; ++q) {
      int i = t + q * PBLK;
      if (i < m) {
        unsigned p = tok2[e0 + i];
        int g = (int)((p & 0x1FFFFu) >> GSHIFT);
        myg[q] = g;
        mytok[q] = p;
        myrank[q] = atomicAdd(&hist[g], 1);
      } else {
        myg[q] = -1;
      }
    }
    __syncthreads();

    sc[t] = hist[t];
    if (t < NGROUP && hist[t] > 0) gbase[t] = atomicAdd(&gcnt2[t], hist[t]);
    __syncthreads();
    for (int off = 1; off < 256; off <<= 1) {
      int add = (t >= off) ? sc[t - off] : 0;
      __syncthreads();
      sc[t] += add;
      __syncthreads();
    }
    scanoff[t] = sc[t] - hist[t];
    __syncthreads();

    #pragma unroll
    for (int q = 0; q < EPT; ++q) {
      if (myg[q] >= 0) {
        int pos = scanoff[myg[q]] + myrank[q];
        buf[pos] = mytok[q];
        gid[pos] = (unsigned char)myg[q];
      }
    }
    __syncthreads();

    for (int i = t; i < m; i += PBLK) {
      int g = gid[i];
      int addr = gbase[g] + (i - scanoff[g]);
      if (addr < GCAP) part2[(size_t)g * GCAP + addr] = buf[i];
    }
  } else {
    // ---------------- gather (node per oct) ----------------
#if !HW_FP8
    __shared__ float tbl[256];
    {
      int t = threadIdx.x;
      if (t < 256) {
        int e = (t >> 3) & 15;
        int m = t & 7;
        float v = e ? ldexpf((float)(8 + m), e - 10) : ldexpf((float)m, -9);
        tbl[t] = (t & 0x80) ? -v : v;
      }
    }
    __syncthreads();
#endif
    int lane = threadIdx.x & 63;
    int oct = lane >> 3;
    int lo = lane & 7;
    int gbid = blockIdx.x - NCHUNK;
    int wid = (gbid * PBLK + (int)threadIdx.x) >> 6;
    const int nw = (GATB * PBLK) >> 6;

    float bj[8];
    #pragma unroll
    for (int k = 0; k < 8; ++k) bj[k] = bias[colOfPos(lo * 8 + k)];

    float ls[8], lq[8];
    #pragma unroll
    for (int k = 0; k < 8; ++k) { ls[k] = 0.f; lq[k] = 0.f; }

    for (int nb = wid * 8; nb < N_NODES; nb += nw * 8) {
      int n = nb + oct;
      bool valid = n < N_NODES;
      int start = valid ? rowptr[n] : 0;
      int end = valid ? rowptr[n + 1] : 0;

      float acc[8];
      #pragma unroll
      for (int k = 0; k < 8; ++k) acc[k] = 0.f;

      for (int bse = start; bse < end; bse += 8) {
        int m = end - bse;
        m = m < 8 ? m : 8;
        int e = bse + lo;
        int s = (e < end) ? csr[e] : 0;
        uint2 vv[8];
        #pragma unroll
        for (int i = 0; i < 8; ++i) {
          int si = __shfl(s, i, 8);          // broadcast within oct
          vv[i] = yf8[(size_t)si * 8 + lo];  // row-0 fallback for tail
        }
        #pragma unroll
        for (int i = 0; i < 8; ++i) {
          if (i < m) {
#if HW_FP8
            floatx2 p0 = __builtin_amdgcn_cvt_pk_f32_fp8((int)vv[i].x, false);
            floatx2 p1 = __builtin_amdgcn_cvt_pk_f32_fp8((int)vv[i].x, true);
            floatx2 p2 = __builtin_amdgcn_cvt_pk_f32_fp8((int)vv[i].y, false);
            floatx2 p3 = __builtin_amdgcn_cvt_pk_f32_fp8((int)vv[i].y, true);
            acc[0] += p0[0];
            acc[1] += p0[1];
            acc[2] += p1[0];
            acc[3] += p1[1];
            acc[4] += p2[0];
            acc[5] += p2[1];
            acc[6] += p3[0];
            acc[7] += p3[1];
#else
            acc[0] += tbl[vv[i].x & 255u];
            acc[1] += tbl[(vv[i].x >> 8) & 255u];
            acc[2] += tbl[(vv[i].x >> 16) & 255u];
            acc[3] += tbl[vv[i].x >> 24];
            acc[4] += tbl[vv[i].y & 255u];
            acc[5] += tbl[(vv[i].y >> 8) & 255u];
            acc[6] += tbl[(vv[i].y >> 16) & 255u];
            acc[7] += tbl[vv[i].y >> 24];
#endif
          }
        }
      }

      if (valid) {
        int deg = end - start;
        float inv = 1.f / (float)(deg > 1 ? deg : 1);
        uint4 ov = *reinterpret_cast<const uint4*>(otherbf +
                                                   (size_t)n * (HID / 2) +
                                                   lo * 4);
        float v[8];
        v[0] = fmaf(acc[0], inv, bj[0]) + bflo(ov.x);
        v[1] = fmaf(acc[1], inv, bj[1]) + bfhi(ov.x);
        v[2] = fmaf(acc[2], inv, bj[2]) + bflo(ov.y);
        v[3] = fmaf(acc[3], inv, bj[3]) + bfhi(ov.y);
        v[4] = fmaf(acc[4], inv, bj[4]) + bflo(ov.z);
        v[5] = fmaf(acc[5], inv, bj[5]) + bfhi(ov.z);
        v[6] = fmaf(acc[6], inv, bj[6]) + bflo(ov.w);
        v[7] = fmaf(acc[7], inv, bj[7]) + bfhi(ov.w);
        uint4 cw4;
        cw4.x = f2bf_pack(v[0], v[1]);
        cw4.y = f2bf_pack(v[2], v[3]);
        cw4.z = f2bf_pack(v[4], v[5]);
        cw4.w = f2bf_pack(v[6], v[7]);
        *reinterpret_cast<uint4*>(outCbf + (size_t)n * (HID / 2) + lo * 4) =
            cw4;
        #pragma unroll
        for (int k = 0; k < 8; ++k) {
          ls[k] += v[k];
          lq[k] = fmaf(v[k], v[k], lq[k]);
        }
      }
    }

    int t = threadIdx.x;
    if (t < HID) { ss[t] = 0.f; sq[t] = 0.f; }
    __syncthreads();
    #pragma unroll
    for (int k = 0; k < 8; ++k) {
      atomicAdd(&ss[lo * 8 + k], ls[k]);   // positional
      atomicAdd(&sq[lo * 8 + k], lq[k]);
    }
    __syncthreads();
    if (t < HID) {
      unsafeAtomicAdd(&stats[t], ss[t]);
      unsafeAtomicAdd(&stats[HID + t], sq[t]);
    }
  }
}

// ---------------------------------------------------------------------------
// KD: chsum — fused caccum + hsum, 512 threads (8 waves).  Positional lane
// layout; gamma/beta via colOfPos.  One block per src-group.
// ---------------------------------------------------------------------------
__global__ __launch_bounds__(512) void chsum_kernel(
    const int* __restrict__ gcnt2, const unsigned* __restrict__ part2,
    const unsigned* __restrict__ Cbf, const float* __restrict__ stats,
    const float* __restrict__ gamma, const float* __restrict__ beta,
    const int* __restrict__ batch, float* __restrict__ S1g,
    float* __restrict__ S2g) {
  __shared__ float c[GNODES * NGRAPH];   // 16 KB
  __shared__ float r1[HID * NGRAPH];     // 2 KB
  __shared__ float r2[HID * NGRAPH];     // 2 KB
  int g = blockIdx.x;
  int t = threadIdx.x;

  for (int i = t; i < GNODES * NGRAPH; i += 512) c[i] = 0.f;
  for (int i = t; i < HID * NGRAPH; i += 512) { r1[i] = 0.f; r2[i] = 0.f; }
  __syncthreads();

  int cnt = min(gcnt2[g], GCAP);
  const unsigned* ga = part2 + (size_t)g * GCAP;
  for (int i = t; i < cnt; i += 512) {
    unsigned p = ga[i];
    int sl = (int)(p & (GNODES - 1));
    int b = (int)((p >> 17) & 7u);
    int deg = (int)((p >> 20) & 0x3FFu);
    float w = 1.f / (float)(deg > 1 ? deg : 1);
    atomicAdd(&c[sl * NGRAPH + b], w);
  }
  __syncthreads();

  int lane = t & 63;
  int wv = t >> 6;  // 8 waves
  int cl = colOfPos(lane);

  float inv_n = 1.0f / (float)N_NODES;
  float mu = stats[lane] * inv_n;     // positional
  float var = stats[HID + lane] * inv_n - mu * mu;
  float scl = gamma[cl] * rsqrtf(var + EPSBN);
  float shf = beta[cl] - mu * scl;

  float s1[NGRAPH], s2[NGRAPH];
  #pragma unroll
  for (int b = 0; b < NGRAPH; ++b) { s1[b] = 0.f; s2[b] = 0.f; }

  int nend = N_NODES - (g << GSHIFT);
  nend = nend < GNODES ? nend : GNODES;
  for (int nl = wv; nl < nend; nl += 8) {
    int n = (g << GSHIFT) + nl;
    unsigned u = Cbf[(size_t)n * (HID / 2) + (lane >> 1)];
    float hr = (lane & 1) ? bfhi(u) : bflo(u);
    float h = fmaf(hr, scl, shf);
    h = h > 0.f ? h : 0.f;
    int bn = batch[n];  // wave-uniform -> s_load
    #pragma unroll
    for (int b = 0; b < NGRAPH; ++b) {
      float cb = c[nl * NGRAPH + b];  // wave-uniform LDS broadcast
      s1[b] = fmaf(cb, h, s1[b]);
      s2[b] += (b == bn) ? h : 0.f;
    }
  }

  #pragma unroll
  for (int b = 0; b < NGRAPH; ++b) {
    atomicAdd(&r1[b * HID + lane], s1[b]);   // positional
    atomicAdd(&r2[b * HID + lane], s2[b]);
  }
  __syncthreads();
  for (int i = t; i < HID * NGRAPH; i += 512) {
    unsafeAtomicAdd(&S1g[i], r1[i]);
    unsafeAtomicAdd(&S2g[i], r2[i]);
  }
}

// ---------------------------------------------------------------------------
// KE: finale — out[b,oc] = (S1[b]@W2l + S2[b]@W2r)[oc]/V_b + b2[oc]  (V_b>0)
// S1g/S2g positional: position l holds column colOfPos(l).
// ---------------------------------------------------------------------------
__device__ __forceinline__ int lbound(const int* __restrict__ a, int key) {
  int lo = 0, hi = N_NODES;
  while (lo < hi) {
    int mid = (lo + hi) >> 1;
    if (a[mid] < key) lo = mid + 1; else hi = mid;
  }
  return lo;
}

__global__ __launch_bounds__(512) void finale_kernel(
    const float* __restrict__ S1g, const float* __restrict__ S2g,
    const int* __restrict__ batch, const float* __restrict__ W2l,
    const float* __restrict__ W2r, const float* __restrict__ b2,
    float* __restrict__ out) {
  int t = threadIdx.x;  // 512 = 8 graphs x 64 cols
  int b = t >> 6;
  int oc = t & 63;
  int V = lbound(batch, b + 1) - lbound(batch, b);
  float acc = 0.f;
  for (int l = 0; l < HID; ++l) {
    int k = colOfPos(l);
    acc = fmaf(S1g[b * HID + l], W2l[k * HID + oc], acc);
    acc = fmaf(S2g[b * HID + l], W2r[k * HID + oc], acc);
  }
  out[t] = (V > 0) ? (acc / (float)V + b2[oc]) : 0.f;
}

// ---------------------------------------------------------------------------
extern "C" void kernel_launch(void* const* d_in, const int* in_sizes, int n_in,
                              void* d_out, int out_size, void* d_ws,
                              size_t ws_size, hipStream_t stream) {
  const float* x      = (const float*)d_in[0];
  const int*   ei     = (const int*)d_in[1];
  const int*   batch  = (const int*)d_in[2];
  const float* W1l    = (const float*)d_in[3];
  const float* b1     = (const float*)d_in[4];
  const float* W1r    = (const float*)d_in[5];
  const float* gamma1 = (const float*)d_in[6];
  const float* beta1  = (const float*)d_in[7];
  const float* W2l    = (const float*)d_in[8];
  const float* b2     = (const float*)d_in[9];
  const float* W2r    = (const float*)d_in[10];

  const int* src = ei;            // edge_index[0]
  const int* dst = ei + E_EDGES;  // edge_index[1]

  float* ws = (float*)d_ws;
  size_t off = 0;
  unsigned char* Af8 = (unsigned char*)(ws + off);
  off += (size_t)N_NODES * HID / 4;                       // fp8 y1 (6.4 MB)
  unsigned* Bbf = (unsigned*)(ws + off);
  off += (size_t)N_NODES * (HID / 2);                     // bf16 y2 (12.8 MB)
  unsigned* Cbf = (unsigned*)(ws + off);
  off += (size_t)N_NODES * (HID / 2);                     // bf16 h_raw
  // zero-region start
  int* gcnt     = (int*)(ws + off); off += 256;
  int* gcnt2    = (int*)(ws + off); off += 256;
  float* stats  = ws + off; off += 2 * HID;
  float* S1g    = ws + off; off += NGRAPH * HID;
  float* S2g    = ws + off; off += NGRAPH * HID;
  size_t zero_elems = 256 + 256 + 2 * HID + 2 * NGRAPH * HID;
  // zero-region end
  unsigned* wTbf = (unsigned*)(ws + off); off += 128 * 64;
  int* rowptr   = (int*)(ws + off); off += N_NODES + 1;
  int* csr      = (int*)(ws + off); off += E_EDGES;
  unsigned* tok2 = (unsigned*)(ws + off); off += E_EDGES;
  unsigned* part = (unsigned*)(ws + off); off += (size_t)NGROUP * GCAP;
  // part is reused as part2 after groupcsr consumes it

  hipMemsetAsync(gcnt, 0, zero_elems * sizeof(float), stream);

  // KA: partition || wprep (independent, lean LDS)
  part_wprep_kernel<<<NCHUNK + WPREPB, PBLK, 0, stream>>>(
      src, dst, gcnt, part, W1l, W1r, wTbf);

  // KB: mm1-MFMA || groupcsr (independent given KA)
  mm1_gcsr_kernel<<<MM1B + NGROUP, 512, 0, stream>>>(
      x, wTbf, Af8, Bbf, gcnt, part, batch, rowptr, csr, tok2);

  // KC: partition2 || gather
  part2_gather_kernel<<<NCHUNK + GATB, PBLK, 0, stream>>>(
      tok2, gcnt2, part, (const uint2*)Af8, csr, rowptr, Bbf, b1, Cbf, stats);

  // KD: chsum (fused caccum + hsum, 512 threads)
  chsum_kernel<<<NGROUP, 512, 0, stream>>>(gcnt2, part, Cbf, stats, gamma1,
                                           beta1, batch, S1g, S2g);

  // KE: finale
  finale_kernel<<<1, 512, 0, stream>>>(S1g, S2g, batch, W2l, W2r, b2,
                                       (float*)d_out);
}